// Round 1
// baseline (1808.283 us; speedup 1.0000x reference)
//
#include <hip/hip_runtime.h>
#include <hip/hip_bf16.h>
#include <stdint.h>

#define SEQ    1024
#define NBAT   8
#define EMB    768
#define NHEAD  12
#define MROWS  (NBAT*SEQ)            // 8192
#define SCALE_S 0.03608439182435161f // 1/sqrt(768)

typedef unsigned short u16;
typedef __attribute__((ext_vector_type(8))) short bf16x8;
typedef __attribute__((ext_vector_type(4))) float f32x4;

typedef void __attribute__((address_space(1)))* gas_ptr;
typedef void __attribute__((address_space(3)))* las_ptr;

__device__ __forceinline__ void gload16(const void* g, void* l) {
  __builtin_amdgcn_global_load_lds((gas_ptr)(void*)g, (las_ptr)l, 16, 0, 0);
}

__device__ __forceinline__ u16 f2bf(float f) {
  union { float f; uint32_t u; } a; a.f = f;
  uint32_t r = a.u + 0x7fffu + ((a.u >> 16) & 1u);
  return (u16)(r >> 16);
}
__device__ __forceinline__ uint32_t pack2(float a, float b) {
  return (uint32_t)f2bf(a) | ((uint32_t)f2bf(b) << 16);
}

// ---------------- conversion kernels ----------------
__global__ void k_cvt(const float* __restrict__ s, u16* __restrict__ d, long n) {
  long i = ((long)blockIdx.x*blockDim.x + threadIdx.x)*8;
  if (i >= n) return;
  float4 a = *(const float4*)(s+i);
  float4 b = *(const float4*)(s+i+4);
  uint4 o; o.x = pack2(a.x,a.y); o.y = pack2(a.z,a.w);
  o.z = pack2(b.x,b.y); o.w = pack2(b.z,b.w);
  *(uint4*)(d+i) = o;
}

__global__ void k_cvt3(const float* __restrict__ s0, const float* __restrict__ s1,
                       const float* __restrict__ s2, u16* __restrict__ d0,
                       u16* __restrict__ d1, u16* __restrict__ d2, long n) {
  const float* s = blockIdx.z == 0 ? s0 : (blockIdx.z == 1 ? s1 : s2);
  u16* d = blockIdx.z == 0 ? d0 : (blockIdx.z == 1 ? d1 : d2);
  long i = ((long)blockIdx.x*blockDim.x + threadIdx.x)*8;
  if (i >= n) return;
  float4 a = *(const float4*)(s+i);
  float4 b = *(const float4*)(s+i+4);
  uint4 o; o.x = pack2(a.x,a.y); o.y = pack2(a.z,a.w);
  o.z = pack2(b.x,b.y); o.w = pack2(b.z,b.w);
  *(uint4*)(d+i) = o;
}

// gather head-slice of Wc [768, 9216] -> wcb [768, Gi*768] bf16
__global__ void k_cvtwc(const float* __restrict__ wc, u16* __restrict__ d, int Gi, int h0) {
  long ncol = (long)Gi*EMB;
  long i = ((long)blockIdx.x*blockDim.x + threadIdx.x)*4;
  if (i >= 768*ncol) return;
  long eo = i / ncol, c = i - eo*ncol;
  long g = c / EMB, dd = c - g*EMB;
  const float* s = wc + eo*(long)(NHEAD*EMB) + (h0+g)*EMB + dd;
  float4 a = *(const float4*)s;
  uint2 o; o.x = pack2(a.x,a.y); o.y = pack2(a.z,a.w);
  *(uint2*)(d+i) = o;
}

// ---------------- NT GEMM: C[M,N] = A[M,K] * B[N,K]^T ----------------
// 128x128 tile, BK=32, 4 waves, global_load_lds staging, swizzled LDS reads.
// mode: 0 = bf16 out + col bias; 1 = bf16 out + row bias;
//       2 = f32 out + col bias (store); 3 = f32 accumulate (no bias)
__global__ __launch_bounds__(256) void k_gemm(
    const u16* __restrict__ A, long a_hs, int lda,
    const u16* __restrict__ B, long b_hs, int ldb, int K,
    u16* Cb, float* Cf, long c_hs, int ldc,
    const float* __restrict__ bias, long bias_hs, int mode, int swapxy)
{
  __shared__ u16 lsA[128*32];
  __shared__ u16 lsB[128*32];
  int g = blockIdx.z;
  const u16* Ag = A + (long)g*a_hs;
  const u16* Bg = B + (long)g*b_hs;
  int tm = swapxy ? blockIdx.y : blockIdx.x;
  int tn = swapxy ? blockIdx.x : blockIdx.y;
  int m0 = tm*128, n0 = tn*128;
  int tid = threadIdx.x;
  int w = tid >> 6, l = tid & 63;

  // staging: 1KB chunk = 16 rows x 32 cols; wave w stages chunks 2w,2w+1.
  // content swizzle: phys 16B slot sp in row holds cols (sp ^ ((row>>1)&3))*8
  int srow = l >> 2;
  int scol = ((l & 3) ^ ((l >> 3) & 3)) * 8;
  const u16* ga0 = Ag + (long)(m0 + (2*w)*16   + srow)*lda + scol;
  const u16* ga1 = Ag + (long)(m0 + (2*w+1)*16 + srow)*lda + scol;
  const u16* gb0 = Bg + (long)(n0 + (2*w)*16   + srow)*ldb + scol;
  const u16* gb1 = Bg + (long)(n0 + (2*w+1)*16 + srow)*ldb + scol;
  u16* la0 = lsA + (2*w)*512; u16* la1 = la0 + 512;
  u16* lb0 = lsB + (2*w)*512; u16* lb1 = lb0 + 512;

  f32x4 acc[4][4];
  #pragma unroll
  for (int i = 0; i < 4; ++i)
    #pragma unroll
    for (int j = 0; j < 4; ++j) acc[i][j] = (f32x4)0.0f;

  int wr = w >> 1, wc_ = w & 1;
  int frow = l & 15;
  int sp = (l >> 4) ^ ((frow >> 1) & 3);
  int aoff[4], boff[4];
  #pragma unroll
  for (int i = 0; i < 4; ++i) {
    aoff[i] = (wr*64 + i*16 + frow)*32 + sp*8;
    boff[i] = (wc_*64 + i*16 + frow)*32 + sp*8;
  }

  for (int k0 = 0; k0 < K; k0 += 32) {
    __syncthreads();
    gload16(ga0 + k0, la0);
    gload16(ga1 + k0, la1);
    gload16(gb0 + k0, lb0);
    gload16(gb1 + k0, lb1);
    __syncthreads();
    bf16x8 af[4], bfr[4];
    #pragma unroll
    for (int i = 0; i < 4; ++i) af[i] = *(const bf16x8*)(lsA + aoff[i]);
    #pragma unroll
    for (int j = 0; j < 4; ++j) bfr[j] = *(const bf16x8*)(lsB + boff[j]);
    #pragma unroll
    for (int i = 0; i < 4; ++i)
      #pragma unroll
      for (int j = 0; j < 4; ++j)
        acc[i][j] = __builtin_amdgcn_mfma_f32_16x16x32_bf16(af[i], bfr[j], acc[i][j], 0, 0, 0);
  }

  u16* Cbg = Cb ? Cb + (long)g*c_hs : (u16*)0;
  const float* bs = bias ? bias + (long)g*bias_hs : (const float*)0;
  int rl = (l >> 4)*4, cl = l & 15;
  #pragma unroll
  for (int i = 0; i < 4; ++i) {
    #pragma unroll
    for (int j = 0; j < 4; ++j) {
      int rb = m0 + wr*64 + i*16 + rl;
      int cb = n0 + wc_*64 + j*16 + cl;
      float cbv = 0.f;
      if ((mode == 0 || mode == 2) && bs) cbv = bs[cb];
      #pragma unroll
      for (int r = 0; r < 4; ++r) {
        int rr = rb + r;
        float v = acc[i][j][r];
        v += (mode == 1) ? bs[rr] : cbv;
        size_t idx = (size_t)rr*(size_t)ldc + cb;
        if (mode <= 1) Cbg[idx] = f2bf(v);
        else if (mode == 2) Cf[idx] = v;
        else Cf[idx] += v;
      }
    }
  }
}

// ---------------- flash attention (causal), QBLK=32, KBLK=64 ----------------
// grid (16 qtile-pairs, 8 batch, Gi heads); 256 threads = 4 waves.
// Q,K: bf16 [8192,768] per head. Vt: bf16 [768,8192] per head.
// H out: bf16 [8192, ldh] at col offset g*768.
__global__ __launch_bounds__(256, 2) void k_attn(
    const u16* __restrict__ qb, const u16* __restrict__ kb,
    const u16* __restrict__ vtb, u16* __restrict__ hb, int ldh)
{
  __shared__ u16 q_ch[32*64];
  __shared__ u16 k_ch[64*64];
  __shared__ u16 v_ch[64*64];
  __shared__ float s_t[32*64];
  __shared__ u16 p_t[32*64];
  __shared__ float e_s[32];

  int pair = blockIdx.x, n = blockIdx.y, g = blockIdx.z;
  const u16* Q  = qb  + (size_t)g*MROWS*EMB + (size_t)n*SEQ*EMB;
  const u16* Kp = kb  + (size_t)g*MROWS*EMB + (size_t)n*SEQ*EMB;
  const u16* Vt = vtb + (size_t)g*EMB*MROWS + (size_t)n*SEQ;
  u16* H = hb + (size_t)(n*SEQ)*ldh + (size_t)g*EMB;

  int tid = threadIdx.x;
  int w = tid >> 6, l = tid & 63;
  int fr = w >> 1;        // row-frag group
  int wcl = w & 1;        // col half
  int strow = l >> 3;                       // row within 1KB staging chunk
  int stswz = ((l & 7) ^ strow) * 8;        // swizzled source col (elems)
  int smrow = tid >> 3, smc = (tid & 7)*8;  // softmax mapping
  int frow = l & 15;
  int frsw = l & 7;

  for (int half = 0; half < 2; ++half) {
    int qt = half ? (31 - pair) : pair;
    int q0 = qt * 32;
    int nt = (qt >> 1) + 1;

    f32x4 acc[12][2];
    #pragma unroll
    for (int i = 0; i < 12; ++i) { acc[i][0] = (f32x4)0.0f; acc[i][1] = (f32x4)0.0f; }
    float m_reg = -1e30f, l_reg = 0.f;

    for (int tt = 0; tt < nt; ++tt) {
      int t0 = tt*64;
      f32x4 sacc[2]; sacc[0] = (f32x4)0.0f; sacc[1] = (f32x4)0.0f;
      for (int e0 = 0; e0 < EMB; e0 += 64) {
        __syncthreads();
        gload16(Q  + (size_t)(q0 + w*8 + strow)*EMB + e0 + stswz, q_ch + w*512);
        gload16(Kp + (size_t)(t0 + (2*w)*8   + strow)*EMB + e0 + stswz, k_ch + (2*w)*512);
        gload16(Kp + (size_t)(t0 + (2*w+1)*8 + strow)*EMB + e0 + stswz, k_ch + (2*w+1)*512);
        __syncthreads();
        #pragma unroll
        for (int kk = 0; kk < 2; ++kk) {
          int so = ((kk*4 + (l>>4)) ^ frsw)*8;
          bf16x8 aq = *(const bf16x8*)(q_ch + (fr*16 + frow)*64 + so);
          #pragma unroll
          for (int c = 0; c < 2; ++c) {
            bf16x8 bk_ = *(const bf16x8*)(k_ch + ((wcl*2 + c)*16 + frow)*64 + so);
            sacc[c] = __builtin_amdgcn_mfma_f32_16x16x32_bf16(aq, bk_, sacc[c], 0, 0, 0);
          }
        }
      }
      #pragma unroll
      for (int c = 0; c < 2; ++c)
        #pragma unroll
        for (int r = 0; r < 4; ++r)
          s_t[(fr*16 + (l>>4)*4 + r)*64 + wcl*32 + c*16 + (l & 15)] = sacc[c][r]*SCALE_S;
      __syncthreads();
      // online softmax, 8 threads per row
      {
        int qg = q0 + smrow;
        float v[8]; float mx = -1e30f;
        #pragma unroll
        for (int j = 0; j < 8; ++j) {
          float s = s_t[smrow*64 + smc + j];
          if (t0 + smc + j > qg) s = -1e30f;
          v[j] = s; mx = fmaxf(mx, s);
        }
        mx = fmaxf(mx, __shfl_xor(mx, 1));
        mx = fmaxf(mx, __shfl_xor(mx, 2));
        mx = fmaxf(mx, __shfl_xor(mx, 4));
        float mn = fmaxf(m_reg, mx);
        float esc = __expf(m_reg - mn);
        float ps = 0.f; u16 pk[8];
        #pragma unroll
        for (int j = 0; j < 8; ++j) { float p = __expf(v[j] - mn); ps += p; pk[j] = f2bf(p); }
        ps += __shfl_xor(ps, 1); ps += __shfl_xor(ps, 2); ps += __shfl_xor(ps, 4);
        l_reg = l_reg*esc + ps; m_reg = mn;
        if ((tid & 7) == 0) e_s[smrow] = esc;
        uint4 pv;
        pv.x = (uint32_t)pk[0] | ((uint32_t)pk[1] << 16);
        pv.y = (uint32_t)pk[2] | ((uint32_t)pk[3] << 16);
        pv.z = (uint32_t)pk[4] | ((uint32_t)pk[5] << 16);
        pv.w = (uint32_t)pk[6] | ((uint32_t)pk[7] << 16);
        *(uint4*)(p_t + smrow*64 + (((tid & 7) ^ (smrow & 7))*8)) = pv;
      }
      __syncthreads();
      // rescale accumulator
      float er[4];
      #pragma unroll
      for (int r = 0; r < 4; ++r) er[r] = e_s[fr*16 + (l>>4)*4 + r];
      #pragma unroll
      for (int ch = 0; ch < 12; ++ch)
        #pragma unroll
        for (int c = 0; c < 2; ++c)
          #pragma unroll
          for (int r = 0; r < 4; ++r) acc[ch][c][r] *= er[r];
      // P fragments
      bf16x8 pa[2];
      #pragma unroll
      for (int kk = 0; kk < 2; ++kk)
        pa[kk] = *(const bf16x8*)(p_t + (fr*16 + frow)*64 + ((kk*4 + (l>>4)) ^ frsw)*8);
      // PV over 12 column chunks of 64
      #pragma unroll
      for (int ch = 0; ch < 12; ++ch) {
        __syncthreads();
        gload16(Vt + (size_t)(ch*64 + (2*w)*8   + strow)*MROWS + t0 + stswz, v_ch + (2*w)*512);
        gload16(Vt + (size_t)(ch*64 + (2*w+1)*8 + strow)*MROWS + t0 + stswz, v_ch + (2*w+1)*512);
        __syncthreads();
        #pragma unroll
        for (int c = 0; c < 2; ++c) {
          #pragma unroll
          for (int kk = 0; kk < 2; ++kk) {
            bf16x8 vb = *(const bf16x8*)(v_ch + ((wcl*2 + c)*16 + frow)*64 + ((kk*4 + (l>>4)) ^ frsw)*8);
            acc[ch][c] = __builtin_amdgcn_mfma_f32_16x16x32_bf16(pa[kk], vb, acc[ch][c], 0, 0, 0);
          }
        }
      }
    }
    // epilogue: divide by l, store bf16
    if ((tid & 7) == 0) e_s[smrow] = l_reg;
    __syncthreads();
    float linv[4];
    #pragma unroll
    for (int r = 0; r < 4; ++r) linv[r] = 1.0f / e_s[fr*16 + (l>>4)*4 + r];
    #pragma unroll
    for (int ch = 0; ch < 12; ++ch)
      #pragma unroll
      for (int c = 0; c < 2; ++c) {
        int col = ch*64 + wcl*32 + c*16 + (l & 15);
        #pragma unroll
        for (int r = 0; r < 4; ++r) {
          int row = q0 + fr*16 + (l>>4)*4 + r;
          H[(size_t)row*ldh + col] = f2bf(acc[ch][c][r]*linv[r]);
        }
      }
    __syncthreads();
  }
}

// ---------------- host ----------------
extern "C" void kernel_launch(void* const* d_in, const int* in_sizes, int n_in,
                              void* d_out, int out_size, void* d_ws, size_t ws_size,
                              hipStream_t stream) {
  const float* x  = (const float*)d_in[0];
  const float* Wq = (const float*)d_in[1];
  const float* bq = (const float*)d_in[2];
  const float* Wk = (const float*)d_in[3];
  const float* bk = (const float*)d_in[4];
  const float* Wv = (const float*)d_in[5];
  const float* bv = (const float*)d_in[6];
  const float* Wc = (const float*)d_in[7];
  const float* bc = (const float*)d_in[8];
  float* out = (float*)d_out;

  const size_t XB  = (size_t)MROWS*EMB*sizeof(u16);   // 12,582,912
  const size_t WHB = (size_t)EMB*EMB*sizeof(u16);     // 1,179,648
  const size_t per_g = 4*WHB + 4*XB;
  long long avail = (long long)ws_size - (long long)XB - 4096;
  int G = (int)(avail / (long long)per_g);
  if (G < 1) G = 1;
  if (G > NHEAD) G = NHEAD;

  char* ws = (char*)d_ws;
  u16* xb  = (u16*)ws;  ws += XB;
  u16* wqb = (u16*)ws;  ws += (size_t)G*WHB;
  u16* wkb = (u16*)ws;  ws += (size_t)G*WHB;
  u16* wvb = (u16*)ws;  ws += (size_t)G*WHB;
  u16* wcb = (u16*)ws;  ws += (size_t)G*WHB;
  u16* qb  = (u16*)ws;  ws += (size_t)G*XB;
  u16* kb  = (u16*)ws;  ws += (size_t)G*XB;
  u16* vtb = (u16*)ws;  ws += (size_t)G*XB;
  u16* hbf = (u16*)ws;  ws += (size_t)G*XB;

  k_cvt<<<dim3(3072), dim3(256), 0, stream>>>(x, xb, (long)MROWS*EMB);

  for (int h0 = 0; h0 < NHEAD; h0 += G) {
    int Gi = (G < NHEAD - h0) ? G : (NHEAD - h0);
    long nw = (long)Gi*EMB*EMB;
    k_cvt3<<<dim3((unsigned)(nw/8/256), 1, 3), dim3(256), 0, stream>>>(
        Wq + (size_t)h0*EMB*EMB, Wk + (size_t)h0*EMB*EMB, Wv + (size_t)h0*EMB*EMB,
        wqb, wkb, wvb, nw);
    k_cvtwc<<<dim3((unsigned)((768L*Gi*EMB/4)/256)), dim3(256), 0, stream>>>(Wc, wcb, Gi, h0);
    // Q = x*Wq^T + bq  -> bf16 [8192,768] per head
    k_gemm<<<dim3(64, 6, Gi), dim3(256), 0, stream>>>(
        xb, 0L, EMB, wqb, (long)EMB*EMB, EMB, EMB,
        qb, (float*)0, (long)MROWS*EMB, EMB, bq + (size_t)h0*EMB, (long)EMB, 0, 0);
    // K
    k_gemm<<<dim3(64, 6, Gi), dim3(256), 0, stream>>>(
        xb, 0L, EMB, wkb, (long)EMB*EMB, EMB, EMB,
        kb, (float*)0, (long)MROWS*EMB, EMB, bk + (size_t)h0*EMB, (long)EMB, 0, 0);
    // Vt = (x*Wv^T + bv)^T  (compute Wv*x^T directly) -> bf16 [768,8192] per head
    k_gemm<<<dim3(64, 6, Gi), dim3(256), 0, stream>>>(
        wvb, (long)EMB*EMB, EMB, xb, 0L, EMB, EMB,
        vtb, (float*)0, (long)MROWS*EMB, MROWS, bv + (size_t)h0*EMB, (long)EMB, 1, 1);
    // flash attention -> hbf [8192, Gi*768]
    k_attn<<<dim3(16, NBAT, Gi), dim3(256), 0, stream>>>(qb, kb, vtb, hbf, Gi*EMB);
    // out += heads_group * Wc_group^T (+bc on first group)
    k_gemm<<<dim3(64, 6, 1), dim3(256), 0, stream>>>(
        hbf, 0L, Gi*EMB, wcb, 0L, Gi*EMB, Gi*EMB,
        (u16*)0, out, 0L, EMB, (h0 == 0 ? bc : (const float*)0), 0L, (h0 == 0 ? 2 : 3), 0);
  }
}

// Round 2
// 1355.243 us; speedup vs baseline: 1.3343x; 1.3343x over previous
//
#include <hip/hip_runtime.h>
#include <hip/hip_bf16.h>
#include <stdint.h>

#define SEQ    1024
#define NBAT   8
#define EMB    768
#define NHEAD  12
#define MROWS  (NBAT*SEQ)            // 8192
#define SCALE_S 0.03608439182435161f // 1/sqrt(768)

typedef unsigned short u16;
typedef __attribute__((ext_vector_type(8))) short bf16x8;
typedef __attribute__((ext_vector_type(4))) float f32x4;

typedef void __attribute__((address_space(1)))* gas_ptr;
typedef void __attribute__((address_space(3)))* las_ptr;

__device__ __forceinline__ void gload16(const void* g, void* l) {
  __builtin_amdgcn_global_load_lds((gas_ptr)(void*)g, (las_ptr)l, 16, 0, 0);
}

#define VMCNT0 asm volatile("s_waitcnt vmcnt(0)" ::: "memory")
#define VMCNT2 asm volatile("s_waitcnt vmcnt(2)" ::: "memory")
#define VMCNT4 asm volatile("s_waitcnt vmcnt(4)" ::: "memory")
#define LGKM0  asm volatile("s_waitcnt lgkmcnt(0)" ::: "memory")
#define BARRIER asm volatile("s_barrier" ::: "memory")

__device__ __forceinline__ u16 f2bf(float f) {
  union { float f; uint32_t u; } a; a.f = f;
  uint32_t r = a.u + 0x7fffu + ((a.u >> 16) & 1u);
  return (u16)(r >> 16);
}
__device__ __forceinline__ uint32_t pack2(float a, float b) {
  return (uint32_t)f2bf(a) | ((uint32_t)f2bf(b) << 16);
}

// ---------------- conversion kernels ----------------
__global__ void k_cvt(const float* __restrict__ s, u16* __restrict__ d, long n) {
  long i = ((long)blockIdx.x*blockDim.x + threadIdx.x)*8;
  if (i >= n) return;
  float4 a = *(const float4*)(s+i);
  float4 b = *(const float4*)(s+i+4);
  uint4 o; o.x = pack2(a.x,a.y); o.y = pack2(a.z,a.w);
  o.z = pack2(b.x,b.y); o.w = pack2(b.z,b.w);
  *(uint4*)(d+i) = o;
}

__global__ void k_cvt3(const float* __restrict__ s0, const float* __restrict__ s1,
                       const float* __restrict__ s2, u16* __restrict__ d0,
                       u16* __restrict__ d1, u16* __restrict__ d2, long n) {
  const float* s = blockIdx.z == 0 ? s0 : (blockIdx.z == 1 ? s1 : s2);
  u16* d = blockIdx.z == 0 ? d0 : (blockIdx.z == 1 ? d1 : d2);
  long i = ((long)blockIdx.x*blockDim.x + threadIdx.x)*8;
  if (i >= n) return;
  float4 a = *(const float4*)(s+i);
  float4 b = *(const float4*)(s+i+4);
  uint4 o; o.x = pack2(a.x,a.y); o.y = pack2(a.z,a.w);
  o.z = pack2(b.x,b.y); o.w = pack2(b.z,b.w);
  *(uint4*)(d+i) = o;
}

// gather head-slice of Wc [768, 9216] -> wcb [768, Gi*768] bf16
__global__ void k_cvtwc(const float* __restrict__ wc, u16* __restrict__ d, int Gi, int h0) {
  long ncol = (long)Gi*EMB;
  long i = ((long)blockIdx.x*blockDim.x + threadIdx.x)*4;
  if (i >= 768*ncol) return;
  long eo = i / ncol, c = i - eo*ncol;
  long g = c / EMB, dd = c - g*EMB;
  const float* s = wc + eo*(long)(NHEAD*EMB) + (h0+g)*EMB + dd;
  float4 a = *(const float4*)s;
  uint2 o; o.x = pack2(a.x,a.y); o.y = pack2(a.z,a.w);
  *(uint2*)(d+i) = o;
}

// ---------------- NT GEMM: C[M,N] = A[M,K] * B[N,K]^T ----------------
// 128x128 tile, BK=32, 4 waves, 3-buffer pipelined global_load_lds staging.
// mode: 0 = bf16 out + col bias; 1 = bf16 out + row bias;
//       2 = f32 out + col bias (store); 3 = f32 accumulate (no bias)
__global__ __launch_bounds__(256) void k_gemm(
    const u16* __restrict__ A, long a_hs, int lda,
    const u16* __restrict__ B, long b_hs, int ldb, int K,
    u16* Cb, float* Cf, long c_hs, int ldc,
    const float* __restrict__ bias, const float* __restrict__ bias2,
    long bias_hs, int gsplit, int mode, int swapxy)
{
  __shared__ u16 lsA[3*4096];
  __shared__ u16 lsB[3*4096];
  int g = blockIdx.z;
  const u16* Ag = A + (long)g*a_hs;
  const u16* Bg = B + (long)g*b_hs;
  int tm = swapxy ? blockIdx.y : blockIdx.x;
  int tn = swapxy ? blockIdx.x : blockIdx.y;
  int m0 = tm*128, n0 = tn*128;
  int tid = threadIdx.x;
  int w = tid >> 6, l = tid & 63;

  // staging: 1KB chunk = 16 rows x 32 cols; wave w stages chunks 2w,2w+1.
  int srow = l >> 2;
  int scol = ((l & 3) ^ ((l >> 3) & 3)) * 8;
  const u16* ga0 = Ag + (long)(m0 + (2*w)*16   + srow)*lda + scol;
  const u16* ga1 = Ag + (long)(m0 + (2*w+1)*16 + srow)*lda + scol;
  const u16* gb0 = Bg + (long)(n0 + (2*w)*16   + srow)*ldb + scol;
  const u16* gb1 = Bg + (long)(n0 + (2*w+1)*16 + srow)*ldb + scol;

#define GSTAGE(k0, buf) do { \
    gload16(ga0 + (k0), lsA + (buf)*4096 + (2*w)*512); \
    gload16(ga1 + (k0), lsA + (buf)*4096 + (2*w+1)*512); \
    gload16(gb0 + (k0), lsB + (buf)*4096 + (2*w)*512); \
    gload16(gb1 + (k0), lsB + (buf)*4096 + (2*w+1)*512); \
  } while(0)

  f32x4 acc[4][4];
  #pragma unroll
  for (int i = 0; i < 4; ++i)
    #pragma unroll
    for (int j = 0; j < 4; ++j) acc[i][j] = (f32x4)0.0f;

  int wr = w >> 1, wc_ = w & 1;
  int frow = l & 15;
  int sp = (l >> 4) ^ ((frow >> 1) & 3);
  int aoff[4], boff[4];
  #pragma unroll
  for (int i = 0; i < 4; ++i) {
    aoff[i] = (wr*64 + i*16 + frow)*32 + sp*8;
    boff[i] = (wc_*64 + i*16 + frow)*32 + sp*8;
  }

  int nt = K >> 5;   // K-steps of 32 (K >= 64 assumed)
  GSTAGE(0, 0);
  GSTAGE(32, 1);
  VMCNT4; BARRIER;
  int cur = 0;
  for (int t = 0; t < nt; ++t) {
    if (t + 2 < nt) {
      int nb = cur + 2; if (nb >= 3) nb -= 3;
      GSTAGE((t+2) << 5, nb);
    }
    const u16* la = lsA + cur*4096;
    const u16* lb = lsB + cur*4096;
    bf16x8 af[4], bfr[4];
    #pragma unroll
    for (int i = 0; i < 4; ++i) af[i] = *(const bf16x8*)(la + aoff[i]);
    #pragma unroll
    for (int j = 0; j < 4; ++j) bfr[j] = *(const bf16x8*)(lb + boff[j]);
    #pragma unroll
    for (int i = 0; i < 4; ++i)
      #pragma unroll
      for (int j = 0; j < 4; ++j)
        acc[i][j] = __builtin_amdgcn_mfma_f32_16x16x32_bf16(af[i], bfr[j], acc[i][j], 0, 0, 0);
    if (t + 2 < nt) { VMCNT4; } else { VMCNT0; }
    LGKM0; BARRIER;
    cur = (cur == 2) ? 0 : cur + 1;
  }
#undef GSTAGE

  u16* Cbg = Cb ? Cb + (long)g*c_hs : (u16*)0;
  const float* bsel = (g < gsplit) ? bias : bias2;
  long gi = (g < gsplit) ? g : g - gsplit;
  const float* bs = bsel ? bsel + gi*bias_hs : (const float*)0;
  int rl = (l >> 4)*4, cl = l & 15;
  #pragma unroll
  for (int i = 0; i < 4; ++i) {
    #pragma unroll
    for (int j = 0; j < 4; ++j) {
      int rb = m0 + wr*64 + i*16 + rl;
      int cb = n0 + wc_*64 + j*16 + cl;
      float cbv = 0.f;
      if ((mode == 0 || mode == 2) && bs) cbv = bs[cb];
      #pragma unroll
      for (int r = 0; r < 4; ++r) {
        int rr = rb + r;
        float v = acc[i][j][r];
        v += (mode == 1) ? bs[rr] : cbv;
        size_t idx = (size_t)rr*(size_t)ldc + cb;
        if (mode <= 1) Cbg[idx] = f2bf(v);
        else if (mode == 2) Cf[idx] = v;
        else Cf[idx] += v;
      }
    }
  }
}

// ---------------- flash attention (causal), QBLK=64, KBLK=64, 8 waves ----------------
// grid 1-D: 8 pairs * 8 batch * Gi heads; XCD-clustered decode.
// Q,K: bf16 [8192,768] per head. Vt: bf16 [768,8192] per head.
__global__ __launch_bounds__(512, 1) void k_attn(
    const u16* __restrict__ qb, const u16* __restrict__ kb,
    const u16* __restrict__ vtb, u16* __restrict__ hb, int ldh)
{
  __shared__ u16 qkls[3*8192];   // per buf: 4096 Q elems + 4096 K elems
  __shared__ u16 vls[3*8192];    // per buf: 128 e-rows x 64 t-cols
  __shared__ float s_t[64*68];
  __shared__ u16 p_t[64*64];
  __shared__ float e_s[64];

  int b = blockIdx.x;
  int xcd = b & 7, kk_ = b >> 3;
  int gn = xcd + 8*(kk_ >> 3), pair = kk_ & 7;   // cluster same-(g,n) on one XCD
  int g = gn >> 3, n = gn & 7;

  const u16* Q  = qb  + (size_t)g*MROWS*EMB + (size_t)n*SEQ*EMB;
  const u16* Kp = kb  + (size_t)g*MROWS*EMB + (size_t)n*SEQ*EMB;
  const u16* Vt = vtb + (size_t)g*EMB*MROWS + (size_t)n*SEQ;
  u16* H = hb + (size_t)(n*SEQ)*ldh + (size_t)g*EMB;

  int tid = threadIdx.x;
  int w = tid >> 6, l = tid & 63;
  int qg = w >> 1;                 // 16-row group (0..3)
  int cg = w & 1;                  // QK col half / PV e half
  int frow = l & 15;
  int fsw = frow & 7;
  int srow = tid >> 3;             // staging row 0..63
  int sphys = tid & 7;
  int scol = ((sphys ^ (srow & 7)) << 3);
  u16* qdst = qkls + w*512;
  u16* kdst = qkls + 4096 + w*512;
  u16* vdst0 = vls + w*512;
  u16* vdst1 = vls + 4096 + w*512;

  for (int half = 0; half < 2; ++half) {
    int qt = half ? 15 - pair : pair;
    int q0 = qt * 64;
    int nt = qt + 1;

    f32x4 acc[6][4];
    #pragma unroll
    for (int i = 0; i < 6; ++i)
      #pragma unroll
      for (int j = 0; j < 4; ++j) acc[i][j] = (f32x4)0.0f;
    float m_reg = -1e30f, l_reg = 0.f;

    const u16* Qs = Q + (size_t)(q0 + srow)*EMB + scol;

    for (int tt = 0; tt < nt; ++tt) {
      int t0 = tt*64;
      const u16* Ks = Kp + (size_t)(t0 + srow)*EMB + scol;
      if (tt == 0) {
        gload16(Qs + 0,  qdst);
        gload16(Ks + 0,  kdst);
        gload16(Qs + 64, qdst + 8192);
        gload16(Ks + 64, kdst + 8192);
      }
      VMCNT2; BARRIER;
      // ---- QK^T over 12 e-chunks of 64, 3-deep pipelined ----
      f32x4 sacc[2]; sacc[0] = (f32x4)0.0f; sacc[1] = (f32x4)0.0f;
      int cur = 0;
      for (int c = 0; c < 12; ++c) {
        if (c + 2 < 12) {
          int nb = cur + 2; if (nb >= 3) nb -= 3;
          gload16(Qs + (c+2)*64, qdst + nb*8192);
          gload16(Ks + (c+2)*64, kdst + nb*8192);
        }
        const u16* qbuf = qkls + cur*8192;
        const u16* kbuf = qbuf + 4096;
        __builtin_amdgcn_s_setprio(1);
        #pragma unroll
        for (int kk = 0; kk < 2; ++kk) {
          int so = ((kk*4 + (l>>4)) ^ fsw) << 3;
          bf16x8 aq = *(const bf16x8*)(qbuf + (qg*16 + frow)*64 + so);
          #pragma unroll
          for (int cc = 0; cc < 2; ++cc) {
            bf16x8 bk_ = *(const bf16x8*)(kbuf + ((cg*2 + cc)*16 + frow)*64 + so);
            sacc[cc] = __builtin_amdgcn_mfma_f32_16x16x32_bf16(aq, bk_, sacc[cc], 0, 0, 0);
          }
        }
        __builtin_amdgcn_s_setprio(0);
        if (c + 2 < 12) { VMCNT2; } else { VMCNT0; }
        LGKM0; BARRIER;
        cur = (cur == 2) ? 0 : cur + 1;
      }
      // ---- write S, prefetch V0,V1 under softmax ----
      #pragma unroll
      for (int cc = 0; cc < 2; ++cc)
        #pragma unroll
        for (int r = 0; r < 4; ++r)
          s_t[(qg*16 + (l>>4)*4 + r)*68 + cg*32 + cc*16 + (l&15)] = sacc[cc][r]*SCALE_S;
      const u16* Vs = Vt + (size_t)srow*MROWS + t0 + scol;
      gload16(Vs,                      vdst0);
      gload16(Vs + (size_t)64*MROWS,   vdst1);
      gload16(Vs + (size_t)128*MROWS,  vdst0 + 8192);
      gload16(Vs + (size_t)192*MROWS,  vdst1 + 8192);
      LGKM0; BARRIER;
      // ---- online softmax: 8 threads/row over 64 cols ----
      {
        int qglob = q0 + srow;
        int cbase = t0 + sphys*8;
        float v[8]; float mx = -1e30f;
        #pragma unroll
        for (int j = 0; j < 8; ++j) {
          float s = s_t[srow*68 + sphys*8 + j];
          if (cbase + j > qglob) s = -1e30f;
          v[j] = s; mx = fmaxf(mx, s);
        }
        mx = fmaxf(mx, __shfl_xor(mx, 1));
        mx = fmaxf(mx, __shfl_xor(mx, 2));
        mx = fmaxf(mx, __shfl_xor(mx, 4));
        float mn = fmaxf(m_reg, mx);
        float esc = __expf(m_reg - mn);
        float ps = 0.f; u16 pk[8];
        #pragma unroll
        for (int j = 0; j < 8; ++j) { float p = __expf(v[j] - mn); ps += p; pk[j] = f2bf(p); }
        ps += __shfl_xor(ps, 1); ps += __shfl_xor(ps, 2); ps += __shfl_xor(ps, 4);
        l_reg = l_reg*esc + ps; m_reg = mn;
        if (sphys == 0) e_s[srow] = esc;
        uint4 pv;
        pv.x = (uint32_t)pk[0] | ((uint32_t)pk[1] << 16);
        pv.y = (uint32_t)pk[2] | ((uint32_t)pk[3] << 16);
        pv.z = (uint32_t)pk[4] | ((uint32_t)pk[5] << 16);
        pv.w = (uint32_t)pk[6] | ((uint32_t)pk[7] << 16);
        *(uint4*)(p_t + srow*64 + ((sphys ^ (srow & 7)) << 3)) = pv;
      }
      VMCNT2; LGKM0; BARRIER;   // V0 ready; p_t/e_s visible
      // ---- rescale acc, load P frags ----
      float er[4];
      #pragma unroll
      for (int r = 0; r < 4; ++r) er[r] = e_s[qg*16 + (l>>4)*4 + r];
      #pragma unroll
      for (int i = 0; i < 6; ++i)
        #pragma unroll
        for (int j = 0; j < 4; ++j)
          #pragma unroll
          for (int r = 0; r < 4; ++r) acc[i][j][r] *= er[r];
      bf16x8 pa[2];
      #pragma unroll
      for (int kk = 0; kk < 2; ++kk)
        pa[kk] = *(const bf16x8*)(p_t + (qg*16 + frow)*64 + (((kk*4 + (l>>4)) ^ fsw) << 3));
      bool stage_next = (tt + 1 < nt);
      const u16* Ks2 = Kp + (size_t)(t0 + 64 + srow)*EMB + scol;
      // ---- PV over 6 V-chunks of 128 e-cols, 3-deep pipelined; next-tile QK under tail ----
      #pragma unroll
      for (int c = 0; c < 6; ++c) {
        if (c < 4) {
          int nb = (c + 2) % 3;
          gload16(Vs + (size_t)((c+2)*128)*MROWS,      vdst0 + nb*8192);
          gload16(Vs + (size_t)((c+2)*128 + 64)*MROWS, vdst1 + nb*8192);
        } else if (stage_next) {
          int ch = c - 4;   // next-tile QK chunk 0,1 -> bufs 0,1
          gload16(Qs + ch*64,  qdst + ch*8192);
          gload16(Ks2 + ch*64, kdst + ch*8192);
        }
        const u16* vbuf = vls + (c % 3)*8192;
        __builtin_amdgcn_s_setprio(1);
        #pragma unroll
        for (int cf = 0; cf < 4; ++cf) {
          #pragma unroll
          for (int kk = 0; kk < 2; ++kk) {
            bf16x8 vbf = *(const bf16x8*)(vbuf + (cg*64 + cf*16 + frow)*64 + (((kk*4 + (l>>4)) ^ fsw) << 3));
            acc[c][cf] = __builtin_amdgcn_mfma_f32_16x16x32_bf16(pa[kk], vbf, acc[c][cf], 0, 0, 0);
          }
        }
        __builtin_amdgcn_s_setprio(0);
        if (c < 4) { VMCNT2; }
        else if (c == 4) { if (stage_next) { VMCNT2; } else { VMCNT0; } }
        else { if (stage_next) { VMCNT4; } else { VMCNT0; } }
        LGKM0; BARRIER;
      }
    } // tt
    // ---- epilogue: divide by l, store bf16 ----
    if (sphys == 0) e_s[srow] = l_reg;
    LGKM0; BARRIER;
    float linv[4];
    #pragma unroll
    for (int r = 0; r < 4; ++r) linv[r] = 1.0f / e_s[qg*16 + (l>>4)*4 + r];
    #pragma unroll
    for (int i = 0; i < 6; ++i)
      #pragma unroll
      for (int j = 0; j < 4; ++j) {
        int col = i*128 + cg*64 + j*16 + (l & 15);
        #pragma unroll
        for (int r = 0; r < 4; ++r) {
          int row = q0 + qg*16 + (l>>4)*4 + r;
          H[(size_t)row*ldh + col] = f2bf(acc[i][j][r]*linv[r]);
        }
      }
    VMCNT0; BARRIER;   // drain stores before next half's staging
  } // half
}

// ---------------- host ----------------
extern "C" void kernel_launch(void* const* d_in, const int* in_sizes, int n_in,
                              void* d_out, int out_size, void* d_ws, size_t ws_size,
                              hipStream_t stream) {
  const float* x  = (const float*)d_in[0];
  const float* Wq = (const float*)d_in[1];
  const float* bq = (const float*)d_in[2];
  const float* Wk = (const float*)d_in[3];
  const float* bk = (const float*)d_in[4];
  const float* Wv = (const float*)d_in[5];
  const float* bv = (const float*)d_in[6];
  const float* Wc = (const float*)d_in[7];
  const float* bc = (const float*)d_in[8];
  float* out = (float*)d_out;

  const size_t XB  = (size_t)MROWS*EMB*sizeof(u16);   // 12,582,912
  const size_t WHB = (size_t)EMB*EMB*sizeof(u16);     // 1,179,648
  const size_t per_g = 4*WHB + 4*XB;
  long long avail = (long long)ws_size - (long long)XB - 4096;
  int G = (int)(avail / (long long)per_g);
  if (G < 1) G = 1;
  if (G > NHEAD) G = NHEAD;

  char* ws = (char*)d_ws;
  u16* xb  = (u16*)ws;  ws += XB;
  u16* wqb = (u16*)ws;  ws += (size_t)(2*G)*WHB;   // wq then wk, packed by Gi
  u16* wvb = (u16*)ws;  ws += (size_t)G*WHB;
  u16* wcb = (u16*)ws;  ws += (size_t)G*WHB;
  u16* qb  = (u16*)ws;  ws += (size_t)(2*G)*XB;    // q then k, packed by Gi
  u16* vtb = (u16*)ws;  ws += (size_t)G*XB;
  u16* hbf = (u16*)ws;  ws += (size_t)G*XB;

  k_cvt<<<dim3(3072), dim3(256), 0, stream>>>(x, xb, (long)MROWS*EMB);

  for (int h0 = 0; h0 < NHEAD; h0 += G) {
    int Gi = (G < NHEAD - h0) ? G : (NHEAD - h0);
    long nw = (long)Gi*EMB*EMB;
    k_cvt3<<<dim3((unsigned)(nw/8/256), 1, 3), dim3(256), 0, stream>>>(
        Wq + (size_t)h0*EMB*EMB, Wk + (size_t)h0*EMB*EMB, Wv + (size_t)h0*EMB*EMB,
        wqb, wqb + (size_t)Gi*EMB*EMB, wvb, nw);
    k_cvtwc<<<dim3((unsigned)((768L*Gi*EMB/4)/256)), dim3(256), 0, stream>>>(Wc, wcb, Gi, h0);
    // Q and K in one launch: z = 2*Gi, weights packed wq[0..Gi) wk[Gi..2Gi)
    k_gemm<<<dim3(64, 6, 2*Gi), dim3(256), 0, stream>>>(
        xb, 0L, EMB, wqb, (long)EMB*EMB, EMB, EMB,
        qb, (float*)0, (long)MROWS*EMB, EMB,
        bq + (size_t)h0*EMB, bk + (size_t)h0*EMB, (long)EMB, Gi, 0, 0);
    // Vt = (x*Wv^T + bv)^T  (compute Wv*x^T directly) -> bf16 [768,8192] per head
    k_gemm<<<dim3(64, 6, Gi), dim3(256), 0, stream>>>(
        wvb, (long)EMB*EMB, EMB, xb, 0L, EMB, EMB,
        vtb, (float*)0, (long)MROWS*EMB, MROWS,
        bv + (size_t)h0*EMB, (const float*)0, (long)EMB, 9999, 1, 1);
    // flash attention -> hbf [8192, Gi*768]
    k_attn<<<dim3(8*NBAT*Gi), dim3(512), 0, stream>>>(
        qb, qb + (size_t)Gi*MROWS*EMB, vtb, hbf, Gi*EMB);
    // out += heads_group * Wc_group^T (+bc on first group)
    k_gemm<<<dim3(64, 6, 1), dim3(256), 0, stream>>>(
        hbf, 0L, Gi*EMB, wcb, 0L, Gi*EMB, Gi*EMB,
        (u16*)0, out, 0L, EMB,
        (h0 == 0 ? bc : (const float*)0), (const float*)0, 0L, 9999,
        (h0 == 0 ? 2 : 3), 0);
  }
}

// Round 3
// 1220.535 us; speedup vs baseline: 1.4815x; 1.1104x over previous
//
#include <hip/hip_runtime.h>
#include <hip/hip_bf16.h>
#include <stdint.h>

#define SEQ    1024
#define NBAT   8
#define EMB    768
#define NHEAD  12
#define MROWS  (NBAT*SEQ)            // 8192
#define SCALE_S 0.03608439182435161f // 1/sqrt(768)

typedef unsigned short u16;
typedef __attribute__((ext_vector_type(8))) short bf16x8;
typedef __attribute__((ext_vector_type(4))) float f32x4;

typedef void __attribute__((address_space(1)))* gas_ptr;
typedef void __attribute__((address_space(3)))* las_ptr;

__device__ __forceinline__ void gload16(const void* g, void* l) {
  __builtin_amdgcn_global_load_lds((gas_ptr)(void*)g, (las_ptr)l, 16, 0, 0);
}

#define VMCNT0 asm volatile("s_waitcnt vmcnt(0)" ::: "memory")
#define VMCNT2 asm volatile("s_waitcnt vmcnt(2)" ::: "memory")
#define VMCNT4 asm volatile("s_waitcnt vmcnt(4)" ::: "memory")
#define LGKM0  asm volatile("s_waitcnt lgkmcnt(0)" ::: "memory")
#define BARRIER asm volatile("s_barrier" ::: "memory")

__device__ __forceinline__ u16 f2bf(float f) {
  union { float f; uint32_t u; } a; a.f = f;
  uint32_t r = a.u + 0x7fffu + ((a.u >> 16) & 1u);
  return (u16)(r >> 16);
}
__device__ __forceinline__ uint32_t pack2(float a, float b) {
  return (uint32_t)f2bf(a) | ((uint32_t)f2bf(b) << 16);
}

// ---------------- conversion kernels ----------------
__global__ void k_cvt(const float* __restrict__ s, u16* __restrict__ d, long n) {
  long i = ((long)blockIdx.x*blockDim.x + threadIdx.x)*8;
  if (i >= n) return;
  float4 a = *(const float4*)(s+i);
  float4 b = *(const float4*)(s+i+4);
  uint4 o; o.x = pack2(a.x,a.y); o.y = pack2(a.z,a.w);
  o.z = pack2(b.x,b.y); o.w = pack2(b.z,b.w);
  *(uint4*)(d+i) = o;
}

__global__ void k_cvt3(const float* __restrict__ s0, const float* __restrict__ s1,
                       const float* __restrict__ s2, u16* __restrict__ d0,
                       u16* __restrict__ d1, u16* __restrict__ d2, long n) {
  const float* s = blockIdx.z == 0 ? s0 : (blockIdx.z == 1 ? s1 : s2);
  u16* d = blockIdx.z == 0 ? d0 : (blockIdx.z == 1 ? d1 : d2);
  long i = ((long)blockIdx.x*blockDim.x + threadIdx.x)*8;
  if (i >= n) return;
  float4 a = *(const float4*)(s+i);
  float4 b = *(const float4*)(s+i+4);
  uint4 o; o.x = pack2(a.x,a.y); o.y = pack2(a.z,a.w);
  o.z = pack2(b.x,b.y); o.w = pack2(b.z,b.w);
  *(uint4*)(d+i) = o;
}

// gather head-slice of Wc [768, 9216] -> wcb [768, Gi*768] bf16
__global__ void k_cvtwc(const float* __restrict__ wc, u16* __restrict__ d, int Gi, int h0) {
  long ncol = (long)Gi*EMB;
  long i = ((long)blockIdx.x*blockDim.x + threadIdx.x)*4;
  if (i >= 768*ncol) return;
  long eo = i / ncol, c = i - eo*ncol;
  long g = c / EMB, dd = c - g*EMB;
  const float* s = wc + eo*(long)(NHEAD*EMB) + (h0+g)*EMB + dd;
  float4 a = *(const float4*)s;
  uint2 o; o.x = pack2(a.x,a.y); o.y = pack2(a.z,a.w);
  *(uint2*)(d+i) = o;
}

// ---------------- NT GEMM: C[M,N] = A[M,K] * B[N,K]^T ----------------
// 128x128 tile, BK=32, 4 waves, 3-buffer pipelined global_load_lds staging.
__global__ __launch_bounds__(256) void k_gemm(
    const u16* __restrict__ A, long a_hs, int lda,
    const u16* __restrict__ B, long b_hs, int ldb, int K,
    u16* Cb, float* Cf, long c_hs, int ldc,
    const float* __restrict__ bias, const float* __restrict__ bias2,
    long bias_hs, int gsplit, int mode, int swapxy)
{
  __shared__ u16 lsA[3*4096];
  __shared__ u16 lsB[3*4096];
  int g = blockIdx.z;
  const u16* Ag = A + (long)g*a_hs;
  const u16* Bg = B + (long)g*b_hs;
  int tm = swapxy ? blockIdx.y : blockIdx.x;
  int tn = swapxy ? blockIdx.x : blockIdx.y;
  int m0 = tm*128, n0 = tn*128;
  int tid = threadIdx.x;
  int w = tid >> 6, l = tid & 63;

  int srow = l >> 2;
  int scol = ((l & 3) ^ ((l >> 3) & 3)) * 8;
  const u16* ga0 = Ag + (long)(m0 + (2*w)*16   + srow)*lda + scol;
  const u16* ga1 = Ag + (long)(m0 + (2*w+1)*16 + srow)*lda + scol;
  const u16* gb0 = Bg + (long)(n0 + (2*w)*16   + srow)*ldb + scol;
  const u16* gb1 = Bg + (long)(n0 + (2*w+1)*16 + srow)*ldb + scol;

#define GSTAGE(k0, buf) do { \
    gload16(ga0 + (k0), lsA + (buf)*4096 + (2*w)*512); \
    gload16(ga1 + (k0), lsA + (buf)*4096 + (2*w+1)*512); \
    gload16(gb0 + (k0), lsB + (buf)*4096 + (2*w)*512); \
    gload16(gb1 + (k0), lsB + (buf)*4096 + (2*w+1)*512); \
  } while(0)

  f32x4 acc[4][4];
  #pragma unroll
  for (int i = 0; i < 4; ++i)
    #pragma unroll
    for (int j = 0; j < 4; ++j) acc[i][j] = (f32x4)0.0f;

  int wr = w >> 1, wc_ = w & 1;
  int frow = l & 15;
  int sp = (l >> 4) ^ ((frow >> 1) & 3);
  int aoff[4], boff[4];
  #pragma unroll
  for (int i = 0; i < 4; ++i) {
    aoff[i] = (wr*64 + i*16 + frow)*32 + sp*8;
    boff[i] = (wc_*64 + i*16 + frow)*32 + sp*8;
  }

  int nt = K >> 5;
  GSTAGE(0, 0);
  GSTAGE(32, 1);
  VMCNT4; BARRIER;
  int cur = 0;
  for (int t = 0; t < nt; ++t) {
    if (t + 2 < nt) {
      int nb = cur + 2; if (nb >= 3) nb -= 3;
      GSTAGE((t+2) << 5, nb);
    }
    const u16* la = lsA + cur*4096;
    const u16* lb = lsB + cur*4096;
    bf16x8 af[4], bfr[4];
    #pragma unroll
    for (int i = 0; i < 4; ++i) af[i] = *(const bf16x8*)(la + aoff[i]);
    #pragma unroll
    for (int j = 0; j < 4; ++j) bfr[j] = *(const bf16x8*)(lb + boff[j]);
    #pragma unroll
    for (int i = 0; i < 4; ++i)
      #pragma unroll
      for (int j = 0; j < 4; ++j)
        acc[i][j] = __builtin_amdgcn_mfma_f32_16x16x32_bf16(af[i], bfr[j], acc[i][j], 0, 0, 0);
    if (t + 2 < nt) { VMCNT4; } else { VMCNT0; }
    LGKM0; BARRIER;
    cur = (cur == 2) ? 0 : cur + 1;
  }
#undef GSTAGE

  u16* Cbg = Cb ? Cb + (long)g*c_hs : (u16*)0;
  const float* bsel = (g < gsplit) ? bias : bias2;
  long gi = (g < gsplit) ? g : g - gsplit;
  const float* bs = bsel ? bsel + gi*bias_hs : (const float*)0;
  int rl = (l >> 4)*4, cl = l & 15;
  #pragma unroll
  for (int i = 0; i < 4; ++i) {
    #pragma unroll
    for (int j = 0; j < 4; ++j) {
      int rb = m0 + wr*64 + i*16 + rl;
      int cb = n0 + wc_*64 + j*16 + cl;
      float cbv = 0.f;
      if ((mode == 0 || mode == 2) && bs) cbv = bs[cb];
      #pragma unroll
      for (int r = 0; r < 4; ++r) {
        int rr = rb + r;
        float v = acc[i][j][r];
        v += (mode == 1) ? bs[rr] : cbv;
        size_t idx = (size_t)rr*(size_t)ldc + cb;
        if (mode <= 1) Cbg[idx] = f2bf(v);
        else if (mode == 2) Cf[idx] = v;
        else Cf[idx] += v;
      }
    }
  }
}

// ---------------- flash attention (causal), QBLK=64, KBLK=64, 8 waves ----------------
// Q held in registers for the whole q-tile; QK e-chunks of 128 (8 MFMA/phase).
__global__ __launch_bounds__(512, 2) void k_attn(
    const u16* __restrict__ qb, const u16* __restrict__ kb,
    const u16* __restrict__ vtb, u16* __restrict__ hb, int ldh)
{
  __shared__ u16 kls[3*8192];    // 3 bufs x (64 rows x 128 cols)
  __shared__ u16 vls[3*8192];    // 3 bufs x (128 e-rows x 64 t-cols)
  __shared__ float s_t[64*68];
  __shared__ u16 p_t[64*64];
  __shared__ float e_s[64];

  int b = blockIdx.x;
  int xcd = b & 7, kk_ = b >> 3;
  int gn = xcd + 8*(kk_ >> 3), pair = kk_ & 7;
  int g = gn >> 3, n = gn & 7;

  const u16* Q  = qb  + (size_t)g*MROWS*EMB + (size_t)n*SEQ*EMB;
  const u16* Kp = kb  + (size_t)g*MROWS*EMB + (size_t)n*SEQ*EMB;
  const u16* Vt = vtb + (size_t)g*EMB*MROWS + (size_t)n*SEQ;
  u16* H = hb + (size_t)(n*SEQ)*ldh + (size_t)g*EMB;

  int tid = threadIdx.x;
  int w = tid >> 6, l = tid & 63;
  int qg = w >> 1;                 // 16-row group (0..3)
  int cg = w & 1;                  // col half
  int frow = l & 15;
  int fsw = frow & 7;
  int srow = tid >> 3;             // staging row 0..63
  int sphys = tid & 7;
  int scol = ((sphys ^ (srow & 7)) << 3);

#define KSTAGE(base, pc, buf) do { \
    gload16((base) + (pc)*128,      kls + (buf)*8192 + w*512); \
    gload16((base) + (pc)*128 + 64, kls + (buf)*8192 + 4096 + w*512); \
  } while(0)
#define VSTAGE(vc, buf) do { \
    gload16(Vs + (size_t)((vc)*128)*MROWS,      vls + (buf)*8192 + w*512); \
    gload16(Vs + (size_t)((vc)*128 + 64)*MROWS, vls + (buf)*8192 + 4096 + w*512); \
  } while(0)

  for (int half = 0; half < 2; ++half) {
    int qt = half ? 15 - pair : pair;
    int q0 = qt * 64;
    int nt = qt + 1;

    f32x4 acc[6][4];
    #pragma unroll
    for (int i = 0; i < 6; ++i)
      #pragma unroll
      for (int j = 0; j < 4; ++j) acc[i][j] = (f32x4)0.0f;
    float m_reg = -1e30f, l_reg = 0.f;

    // ---- load Q tile to registers via pipelined LDS pass ----
    const u16* Qs = Q + (size_t)(q0 + srow)*EMB + scol;
    bf16x8 qreg[12][2];
    KSTAGE(Qs, 0, 0);
    KSTAGE(Qs, 1, 1);
    VMCNT2; BARRIER;
    #pragma unroll
    for (int pc = 0; pc < 6; ++pc) {
      if (pc < 4) KSTAGE(Qs, pc+2, (pc+2)%3);
      const u16* qb_ = kls + (pc%3)*8192;
      #pragma unroll
      for (int kk2 = 0; kk2 < 2; ++kk2)
        #pragma unroll
        for (int kkl = 0; kkl < 2; ++kkl)
          qreg[2*pc + kk2][kkl] = *(const bf16x8*)(qb_ + kk2*4096 + (qg*16 + frow)*64
                                                   + (((kkl*4 + (l>>4)) ^ fsw) << 3));
      if (pc < 4) { VMCNT2; } else if (pc == 4) { VMCNT0; }
      LGKM0; BARRIER;
    }

    for (int tt = 0; tt < nt; ++tt) {
      int t0 = tt*64;
      const u16* Ks = Kp + (size_t)(t0 + srow)*EMB + scol;
      const u16* Vs = Vt + (size_t)srow*MROWS + t0 + scol;
      if (tt == 0) { KSTAGE(Ks, 0, 0); KSTAGE(Ks, 1, 1); }
      VMCNT2; BARRIER;

      // ---- QK^T: 6 phases of e-chunk 128, 8 MFMA each ----
      f32x4 sacc[2]; sacc[0] = (f32x4)0.0f; sacc[1] = (f32x4)0.0f;
      #pragma unroll
      for (int c = 0; c < 6; ++c) {
        if (c < 4)       KSTAGE(Ks, c+2, (c+2)%3);
        else if (c == 4) VSTAGE(0, 0);
        else             VSTAGE(1, 1);
        const u16* kb_ = kls + (c%3)*8192;
        __builtin_amdgcn_s_setprio(1);
        #pragma unroll
        for (int kk2 = 0; kk2 < 2; ++kk2) {
          #pragma unroll
          for (int kkl = 0; kkl < 2; ++kkl) {
            int so = ((kkl*4 + (l>>4)) ^ fsw) << 3;
            bf16x8 aq = qreg[2*c + kk2][kkl];
            #pragma unroll
            for (int cc = 0; cc < 2; ++cc) {
              bf16x8 bk_ = *(const bf16x8*)(kb_ + kk2*4096 + ((cg*2 + cc)*16 + frow)*64 + so);
              sacc[cc] = __builtin_amdgcn_mfma_f32_16x16x32_bf16(aq, bk_, sacc[cc], 0, 0, 0);
            }
          }
        }
        __builtin_amdgcn_s_setprio(0);
        if (c < 5) { VMCNT2; LGKM0; BARRIER; }
      }

      // ---- write S ----
      #pragma unroll
      for (int cc = 0; cc < 2; ++cc)
        #pragma unroll
        for (int r = 0; r < 4; ++r)
          s_t[(qg*16 + (l>>4)*4 + r)*68 + cg*32 + cc*16 + (l&15)] = sacc[cc][r]*SCALE_S;
      LGKM0; BARRIER;
      // ---- online softmax: 8 threads/row ----
      {
        int qglob = q0 + srow;
        int cbase = t0 + sphys*8;
        float v[8]; float mx = -1e30f;
        #pragma unroll
        for (int j = 0; j < 8; ++j) {
          float s = s_t[srow*68 + sphys*8 + j];
          if (cbase + j > qglob) s = -1e30f;
          v[j] = s; mx = fmaxf(mx, s);
        }
        mx = fmaxf(mx, __shfl_xor(mx, 1));
        mx = fmaxf(mx, __shfl_xor(mx, 2));
        mx = fmaxf(mx, __shfl_xor(mx, 4));
        float mn = fmaxf(m_reg, mx);
        float esc = __expf(m_reg - mn);
        float ps = 0.f; u16 pk[8];
        #pragma unroll
        for (int j = 0; j < 8; ++j) { float p = __expf(v[j] - mn); ps += p; pk[j] = f2bf(p); }
        ps += __shfl_xor(ps, 1); ps += __shfl_xor(ps, 2); ps += __shfl_xor(ps, 4);
        l_reg = l_reg*esc + ps; m_reg = mn;
        if (sphys == 0) e_s[srow] = esc;
        uint4 pv;
        pv.x = (uint32_t)pk[0] | ((uint32_t)pk[1] << 16);
        pv.y = (uint32_t)pk[2] | ((uint32_t)pk[3] << 16);
        pv.z = (uint32_t)pk[4] | ((uint32_t)pk[5] << 16);
        pv.w = (uint32_t)pk[6] | ((uint32_t)pk[7] << 16);
        *(uint4*)(p_t + srow*64 + ((sphys ^ (srow & 7)) << 3)) = pv;
      }
      VMCNT2; LGKM0; BARRIER;   // V0 landed (all waves) + p_t/e_s visible
      // ---- rescale acc, load P frags ----
      float er[4];
      #pragma unroll
      for (int r = 0; r < 4; ++r) er[r] = e_s[qg*16 + (l>>4)*4 + r];
      #pragma unroll
      for (int i = 0; i < 6; ++i)
        #pragma unroll
        for (int j = 0; j < 4; ++j)
          #pragma unroll
          for (int r = 0; r < 4; ++r) acc[i][j][r] *= er[r];
      bf16x8 pa[2];
      #pragma unroll
      for (int kk = 0; kk < 2; ++kk)
        pa[kk] = *(const bf16x8*)(p_t + (qg*16 + frow)*64 + (((kk*4 + (l>>4)) ^ fsw) << 3));
      bool stage_next = (tt + 1 < nt);
      const u16* Ks2 = Kp + (size_t)(t0 + 64 + srow)*EMB + scol;
      // ---- PV: 6 phases of e-chunk 128 ----
      #pragma unroll
      for (int c = 0; c < 6; ++c) {
        if (c < 4)            VSTAGE(c+2, (c+2)%3);
        else if (stage_next)  { if (c == 4) KSTAGE(Ks2, 0, 0); else KSTAGE(Ks2, 1, 1); }
        const u16* vb_ = vls + (c%3)*8192;
        __builtin_amdgcn_s_setprio(1);
        #pragma unroll
        for (int cf = 0; cf < 4; ++cf) {
          #pragma unroll
          for (int kk = 0; kk < 2; ++kk) {
            bf16x8 vbf = *(const bf16x8*)(vb_ + (cg*64 + cf*16 + frow)*64 + (((kk*4 + (l>>4)) ^ fsw) << 3));
            acc[c][cf] = __builtin_amdgcn_mfma_f32_16x16x32_bf16(pa[kk], vbf, acc[c][cf], 0, 0, 0);
          }
        }
        __builtin_amdgcn_s_setprio(0);
        if (c < 4)      { VMCNT2; LGKM0; BARRIER; }
        else if (c == 4){ if (stage_next) { VMCNT2; } else { VMCNT0; } LGKM0; BARRIER; }
        // c==5: no wait/barrier; tile-top VMCNT2+BARRIER (or epilogue) covers
      }
    } // tt
    // ---- epilogue ----
    if (sphys == 0) e_s[srow] = l_reg;
    LGKM0; BARRIER;
    float linv[4];
    #pragma unroll
    for (int r = 0; r < 4; ++r) linv[r] = 1.0f / e_s[qg*16 + (l>>4)*4 + r];
    #pragma unroll
    for (int i = 0; i < 6; ++i)
      #pragma unroll
      for (int j = 0; j < 4; ++j) {
        int col = i*128 + cg*64 + j*16 + (l & 15);
        #pragma unroll
        for (int r = 0; r < 4; ++r) {
          int row = q0 + qg*16 + (l>>4)*4 + r;
          H[(size_t)row*ldh + col] = f2bf(acc[i][j][r]*linv[r]);
        }
      }
    BARRIER;   // e_s settled before next half reuses it
  } // half
#undef KSTAGE
#undef VSTAGE
}

// ---------------- host ----------------
extern "C" void kernel_launch(void* const* d_in, const int* in_sizes, int n_in,
                              void* d_out, int out_size, void* d_ws, size_t ws_size,
                              hipStream_t stream) {
  const float* x  = (const float*)d_in[0];
  const float* Wq = (const float*)d_in[1];
  const float* bq = (const float*)d_in[2];
  const float* Wk = (const float*)d_in[3];
  const float* bk = (const float*)d_in[4];
  const float* Wv = (const float*)d_in[5];
  const float* bv = (const float*)d_in[6];
  const float* Wc = (const float*)d_in[7];
  const float* bc = (const float*)d_in[8];
  float* out = (float*)d_out;

  const size_t XB  = (size_t)MROWS*EMB*sizeof(u16);
  const size_t WHB = (size_t)EMB*EMB*sizeof(u16);
  const size_t per_g = 4*WHB + 4*XB;
  long long avail = (long long)ws_size - (long long)XB - 4096;
  int G = (int)(avail / (long long)per_g);
  if (G < 1) G = 1;
  if (G > NHEAD) G = NHEAD;

  char* ws = (char*)d_ws;
  u16* xb  = (u16*)ws;  ws += XB;
  u16* wqb = (u16*)ws;  ws += (size_t)(2*G)*WHB;
  u16* wvb = (u16*)ws;  ws += (size_t)G*WHB;
  u16* wcb = (u16*)ws;  ws += (size_t)G*WHB;
  u16* qb  = (u16*)ws;  ws += (size_t)(2*G)*XB;
  u16* vtb = (u16*)ws;  ws += (size_t)G*XB;
  u16* hbf = (u16*)ws;  ws += (size_t)G*XB;

  k_cvt<<<dim3(3072), dim3(256), 0, stream>>>(x, xb, (long)MROWS*EMB);

  for (int h0 = 0; h0 < NHEAD; h0 += G) {
    int Gi = (G < NHEAD - h0) ? G : (NHEAD - h0);
    long nw = (long)Gi*EMB*EMB;
    k_cvt3<<<dim3((unsigned)(nw/8/256), 1, 3), dim3(256), 0, stream>>>(
        Wq + (size_t)h0*EMB*EMB, Wk + (size_t)h0*EMB*EMB, Wv + (size_t)h0*EMB*EMB,
        wqb, wqb + (size_t)Gi*EMB*EMB, wvb, nw);
    k_cvtwc<<<dim3((unsigned)((768L*Gi*EMB/4)/256)), dim3(256), 0, stream>>>(Wc, wcb, Gi, h0);
    k_gemm<<<dim3(64, 6, 2*Gi), dim3(256), 0, stream>>>(
        xb, 0L, EMB, wqb, (long)EMB*EMB, EMB, EMB,
        qb, (float*)0, (long)MROWS*EMB, EMB,
        bq + (size_t)h0*EMB, bk + (size_t)h0*EMB, (long)EMB, Gi, 0, 0);
    k_gemm<<<dim3(64, 6, Gi), dim3(256), 0, stream>>>(
        wvb, (long)EMB*EMB, EMB, xb, 0L, EMB, EMB,
        vtb, (float*)0, (long)MROWS*EMB, MROWS,
        bv + (size_t)h0*EMB, (const float*)0, (long)EMB, 9999, 1, 1);
    k_attn<<<dim3(8*NBAT*Gi), dim3(512), 0, stream>>>(
        qb, qb + (size_t)Gi*MROWS*EMB, vtb, hbf, Gi*EMB);
    k_gemm<<<dim3(64, 6, 1), dim3(256), 0, stream>>>(
        hbf, 0L, Gi*EMB, wcb, 0L, Gi*EMB, Gi*EMB,
        (u16*)0, out, 0L, EMB,
        (h0 == 0 ? bc : (const float*)0), (const float*)0, 0L, 9999,
        (h0 == 0 ? 2 : 3), 0);
  }
}

// Round 4
// 1144.484 us; speedup vs baseline: 1.5800x; 1.0665x over previous
//
#include <hip/hip_runtime.h>
#include <hip/hip_bf16.h>
#include <stdint.h>

#define SEQ    1024
#define NBAT   8
#define EMB    768
#define NHEAD  12
#define MROWS  (NBAT*SEQ)            // 8192
#define SCALE_S 0.03608439182435161f // 1/sqrt(768)

typedef unsigned short u16;
typedef __attribute__((ext_vector_type(8))) short bf16x8;
typedef __attribute__((ext_vector_type(4))) float f32x4;

typedef void __attribute__((address_space(1)))* gas_ptr;
typedef void __attribute__((address_space(3)))* las_ptr;

__device__ __forceinline__ void gload16(const void* g, void* l) {
  __builtin_amdgcn_global_load_lds((gas_ptr)(void*)g, (las_ptr)l, 16, 0, 0);
}

#define VMCNT0 asm volatile("s_waitcnt vmcnt(0)" ::: "memory")
#define VMCNT2 asm volatile("s_waitcnt vmcnt(2)" ::: "memory")
#define VMCNT4 asm volatile("s_waitcnt vmcnt(4)" ::: "memory")
#define LGKM0  asm volatile("s_waitcnt lgkmcnt(0)" ::: "memory")
#define BARRIER asm volatile("s_barrier" ::: "memory")

__device__ __forceinline__ u16 f2bf(float f) {
  union { float f; uint32_t u; } a; a.f = f;
  uint32_t r = a.u + 0x7fffu + ((a.u >> 16) & 1u);
  return (u16)(r >> 16);
}
__device__ __forceinline__ uint32_t pack2(float a, float b) {
  return (uint32_t)f2bf(a) | ((uint32_t)f2bf(b) << 16);
}

// ---------------- conversion kernels ----------------
__global__ void k_cvt(const float* __restrict__ s, u16* __restrict__ d, long n) {
  long i = ((long)blockIdx.x*blockDim.x + threadIdx.x)*8;
  if (i >= n) return;
  float4 a = *(const float4*)(s+i);
  float4 b = *(const float4*)(s+i+4);
  uint4 o; o.x = pack2(a.x,a.y); o.y = pack2(a.z,a.w);
  o.z = pack2(b.x,b.y); o.w = pack2(b.z,b.w);
  *(uint4*)(d+i) = o;
}

__global__ void k_cvt3(const float* __restrict__ s0, const float* __restrict__ s1,
                       const float* __restrict__ s2, u16* __restrict__ d0,
                       u16* __restrict__ d1, u16* __restrict__ d2, long n) {
  const float* s = blockIdx.z == 0 ? s0 : (blockIdx.z == 1 ? s1 : s2);
  u16* d = blockIdx.z == 0 ? d0 : (blockIdx.z == 1 ? d1 : d2);
  long i = ((long)blockIdx.x*blockDim.x + threadIdx.x)*8;
  if (i >= n) return;
  float4 a = *(const float4*)(s+i);
  float4 b = *(const float4*)(s+i+4);
  uint4 o; o.x = pack2(a.x,a.y); o.y = pack2(a.z,a.w);
  o.z = pack2(b.x,b.y); o.w = pack2(b.z,b.w);
  *(uint4*)(d+i) = o;
}

// gather head-slice of Wc [768, 9216] -> wcb [768, Gi*768] bf16
__global__ void k_cvtwc(const float* __restrict__ wc, u16* __restrict__ d, int Gi, int h0) {
  long ncol = (long)Gi*EMB;
  long i = ((long)blockIdx.x*blockDim.x + threadIdx.x)*4;
  if (i >= 768*ncol) return;
  long eo = i / ncol, c = i - eo*ncol;
  long g = c / EMB, dd = c - g*EMB;
  const float* s = wc + eo*(long)(NHEAD*EMB) + (h0+g)*EMB + dd;
  float4 a = *(const float4*)s;
  uint2 o; o.x = pack2(a.x,a.y); o.y = pack2(a.z,a.w);
  *(uint2*)(d+i) = o;
}

// ---------------- 256x256 NT GEMM: C[M,N] = A[M,K]*B[N,K]^T, BK=64, 8 waves ----------------
// Double-buffered LDS (128 KB), 1 barrier + vmcnt(0) per K-tile, 512 MFMA/block/tile.
// mode 0: bf16 out, sliced columns (slice width 768, stride c_hs), col-bias split at gsplit.
// mode 1: bf16 out, plain ldc, row-bias.
__global__ __launch_bounds__(512, 2) void k_gemm256(
    const u16* __restrict__ A, int lda,
    const u16* __restrict__ B, int ldb, int K,
    u16* __restrict__ Cb, long c_hs, int ldc,
    const float* __restrict__ bias, const float* __restrict__ bias2,
    int gsplit, int mode)
{
  __shared__ u16 lsA[2*16384];   // 2 bufs x 256 rows x 64 cols
  __shared__ u16 lsB[2*16384];

  int m0 = blockIdx.x * 256;
  int n0 = blockIdx.y * 256;
  int tid = threadIdx.x;
  int w = tid >> 6, l = tid & 63;
  int wr = w >> 2, wc = w & 3;        // wave tile: rows wr*128, cols wc*64

  // staging: chunk = 8 rows x 64 cols (1 KB). wave w stages chunks 4w..4w+3 (rows 32w..32w+31).
  // lane l -> row l>>3, phys slot l&7 holds source col-slot (l&7)^(l>>3).
  const u16* gA = A + (size_t)(m0 + 32*w + (l>>3))*lda + (((l&7) ^ (l>>3)) << 3);
  const u16* gB = B + (size_t)(n0 + 32*w + (l>>3))*ldb + (((l&7) ^ (l>>3)) << 3);

#define STAGE256(t, buf) do { \
    int k0_ = (t)*64; \
    _Pragma("unroll") \
    for (int c_ = 0; c_ < 4; ++c_) \
      gload16(gA + (size_t)(c_*8)*lda + k0_, lsA + (buf)*16384 + (32*w + 8*c_)*64); \
    _Pragma("unroll") \
    for (int c_ = 0; c_ < 4; ++c_) \
      gload16(gB + (size_t)(c_*8)*ldb + k0_, lsB + (buf)*16384 + (32*w + 8*c_)*64); \
  } while(0)

  f32x4 acc[8][4];
  #pragma unroll
  for (int i = 0; i < 8; ++i)
    #pragma unroll
    for (int j = 0; j < 4; ++j) acc[i][j] = (f32x4)0.0f;

  int nt = K >> 6;
  STAGE256(0, 0);
  for (int t = 0; t < nt; ++t) {
    VMCNT0; BARRIER;
    if (t + 1 < nt) STAGE256(t+1, (t+1)&1);
    const u16* la = lsA + (t&1)*16384;
    const u16* lb = lsB + (t&1)*16384;
    #pragma unroll
    for (int ks = 0; ks < 2; ++ks) {
      int off = (((4*ks + (l>>4)) ^ (l&7)) << 3);
      bf16x8 af[8], bf_[4];
      #pragma unroll
      for (int fi = 0; fi < 8; ++fi)
        af[fi] = *(const bf16x8*)(la + (wr*128 + fi*16 + (l&15))*64 + off);
      #pragma unroll
      for (int fj = 0; fj < 4; ++fj)
        bf_[fj] = *(const bf16x8*)(lb + (wc*64 + fj*16 + (l&15))*64 + off);
      __builtin_amdgcn_s_setprio(1);
      #pragma unroll
      for (int fi = 0; fi < 8; ++fi)
        #pragma unroll
        for (int fj = 0; fj < 4; ++fj)
          acc[fi][fj] = __builtin_amdgcn_mfma_f32_16x16x32_bf16(af[fi], bf_[fj], acc[fi][fj], 0, 0, 0);
      __builtin_amdgcn_s_setprio(0);
    }
  }
#undef STAGE256

  if (mode == 0) {
    int s = n0 / 768;
    int dbase = n0 - s*768 + wc*64;
    const float* bsl = (s < gsplit) ? bias + (size_t)s*768 : bias2 + (size_t)(s - gsplit)*768;
    u16* Cs = Cb + (size_t)s*c_hs;
    #pragma unroll
    for (int fj = 0; fj < 4; ++fj) {
      int dcol = dbase + fj*16 + (l&15);
      float bb = bsl[dcol];
      #pragma unroll
      for (int fi = 0; fi < 8; ++fi) {
        #pragma unroll
        for (int r = 0; r < 4; ++r) {
          int row = m0 + wr*128 + fi*16 + (l>>4)*4 + r;
          Cs[(size_t)row*768 + dcol] = f2bf(acc[fi][fj][r] + bb);
        }
      }
    }
  } else {
    #pragma unroll
    for (int fi = 0; fi < 8; ++fi) {
      #pragma unroll
      for (int r = 0; r < 4; ++r) {
        int row = m0 + wr*128 + fi*16 + (l>>4)*4 + r;
        float bb = bias[row];
        #pragma unroll
        for (int fj = 0; fj < 4; ++fj) {
          int cbn = n0 + wc*64 + fj*16 + (l&15);
          Cb[(size_t)row*ldc + cbn] = f2bf(acc[fi][fj][r] + bb);
        }
      }
    }
  }
}

// ---------------- NT GEMM: 128x128 tile (kept for output projection) ----------------
__global__ __launch_bounds__(256) void k_gemm(
    const u16* __restrict__ A, long a_hs, int lda,
    const u16* __restrict__ B, long b_hs, int ldb, int K,
    u16* Cb, float* Cf, long c_hs, int ldc,
    const float* __restrict__ bias, const float* __restrict__ bias2,
    long bias_hs, int gsplit, int mode, int swapxy)
{
  __shared__ u16 lsA[3*4096];
  __shared__ u16 lsB[3*4096];
  int g = blockIdx.z;
  const u16* Ag = A + (long)g*a_hs;
  const u16* Bg = B + (long)g*b_hs;
  int tm = swapxy ? blockIdx.y : blockIdx.x;
  int tn = swapxy ? blockIdx.x : blockIdx.y;
  int m0 = tm*128, n0 = tn*128;
  int tid = threadIdx.x;
  int w = tid >> 6, l = tid & 63;

  int srow = l >> 2;
  int scol = ((l & 3) ^ ((l >> 3) & 3)) * 8;
  const u16* ga0 = Ag + (long)(m0 + (2*w)*16   + srow)*lda + scol;
  const u16* ga1 = Ag + (long)(m0 + (2*w+1)*16 + srow)*lda + scol;
  const u16* gb0 = Bg + (long)(n0 + (2*w)*16   + srow)*ldb + scol;
  const u16* gb1 = Bg + (long)(n0 + (2*w+1)*16 + srow)*ldb + scol;

#define GSTAGE(k0, buf) do { \
    gload16(ga0 + (k0), lsA + (buf)*4096 + (2*w)*512); \
    gload16(ga1 + (k0), lsA + (buf)*4096 + (2*w+1)*512); \
    gload16(gb0 + (k0), lsB + (buf)*4096 + (2*w)*512); \
    gload16(gb1 + (k0), lsB + (buf)*4096 + (2*w+1)*512); \
  } while(0)

  f32x4 acc[4][4];
  #pragma unroll
  for (int i = 0; i < 4; ++i)
    #pragma unroll
    for (int j = 0; j < 4; ++j) acc[i][j] = (f32x4)0.0f;

  int wr = w >> 1, wc_ = w & 1;
  int frow = l & 15;
  int sp = (l >> 4) ^ ((frow >> 1) & 3);
  int aoff[4], boff[4];
  #pragma unroll
  for (int i = 0; i < 4; ++i) {
    aoff[i] = (wr*64 + i*16 + frow)*32 + sp*8;
    boff[i] = (wc_*64 + i*16 + frow)*32 + sp*8;
  }

  int nt = K >> 5;
  GSTAGE(0, 0);
  GSTAGE(32, 1);
  VMCNT4; BARRIER;
  int cur = 0;
  for (int t = 0; t < nt; ++t) {
    if (t + 2 < nt) {
      int nb = cur + 2; if (nb >= 3) nb -= 3;
      GSTAGE((t+2) << 5, nb);
    }
    const u16* la = lsA + cur*4096;
    const u16* lb = lsB + cur*4096;
    bf16x8 af[4], bfr[4];
    #pragma unroll
    for (int i = 0; i < 4; ++i) af[i] = *(const bf16x8*)(la + aoff[i]);
    #pragma unroll
    for (int j = 0; j < 4; ++j) bfr[j] = *(const bf16x8*)(lb + boff[j]);
    #pragma unroll
    for (int i = 0; i < 4; ++i)
      #pragma unroll
      for (int j = 0; j < 4; ++j)
        acc[i][j] = __builtin_amdgcn_mfma_f32_16x16x32_bf16(af[i], bfr[j], acc[i][j], 0, 0, 0);
    if (t + 2 < nt) { VMCNT4; } else { VMCNT0; }
    LGKM0; BARRIER;
    cur = (cur == 2) ? 0 : cur + 1;
  }
#undef GSTAGE

  u16* Cbg = Cb ? Cb + (long)g*c_hs : (u16*)0;
  const float* bsel = (g < gsplit) ? bias : bias2;
  long gi = (g < gsplit) ? g : g - gsplit;
  const float* bs = bsel ? bsel + gi*bias_hs : (const float*)0;
  int rl = (l >> 4)*4, cl = l & 15;
  #pragma unroll
  for (int i = 0; i < 4; ++i) {
    #pragma unroll
    for (int j = 0; j < 4; ++j) {
      int rb = m0 + wr*64 + i*16 + rl;
      int cb = n0 + wc_*64 + j*16 + cl;
      float cbv = 0.f;
      if ((mode == 0 || mode == 2) && bs) cbv = bs[cb];
      #pragma unroll
      for (int r = 0; r < 4; ++r) {
        int rr = rb + r;
        float v = acc[i][j][r];
        v += (mode == 1) ? bs[rr] : cbv;
        size_t idx = (size_t)rr*(size_t)ldc + cb;
        if (mode <= 1) Cbg[idx] = f2bf(v);
        else if (mode == 2) Cf[idx] = v;
        else Cf[idx] += v;
      }
    }
  }
}

// ---------------- flash attention (causal), QBLK=64, KBLK=64, 8 waves ----------------
__global__ __launch_bounds__(512, 2) void k_attn(
    const u16* __restrict__ qb, const u16* __restrict__ kb,
    const u16* __restrict__ vtb, u16* __restrict__ hb, int ldh)
{
  __shared__ u16 kls[3*8192];
  __shared__ u16 vls[3*8192];
  __shared__ float s_t[64*68];
  __shared__ u16 p_t[64*64];
  __shared__ float e_s[64];

  int b = blockIdx.x;
  int xcd = b & 7, kk_ = b >> 3;
  int gn = xcd + 8*(kk_ >> 3), pair = kk_ & 7;
  int g = gn >> 3, n = gn & 7;

  const u16* Q  = qb  + (size_t)g*MROWS*EMB + (size_t)n*SEQ*EMB;
  const u16* Kp = kb  + (size_t)g*MROWS*EMB + (size_t)n*SEQ*EMB;
  const u16* Vt = vtb + (size_t)g*EMB*MROWS + (size_t)n*SEQ;
  u16* H = hb + (size_t)(n*SEQ)*ldh + (size_t)g*EMB;

  int tid = threadIdx.x;
  int w = tid >> 6, l = tid & 63;
  int qg = w >> 1;
  int cg = w & 1;
  int frow = l & 15;
  int fsw = frow & 7;
  int srow = tid >> 3;
  int sphys = tid & 7;
  int scol = ((sphys ^ (srow & 7)) << 3);

#define KSTAGE(base, pc, buf) do { \
    gload16((base) + (pc)*128,      kls + (buf)*8192 + w*512); \
    gload16((base) + (pc)*128 + 64, kls + (buf)*8192 + 4096 + w*512); \
  } while(0)
#define VSTAGE(vc, buf) do { \
    gload16(Vs + (size_t)((vc)*128)*MROWS,      vls + (buf)*8192 + w*512); \
    gload16(Vs + (size_t)((vc)*128 + 64)*MROWS, vls + (buf)*8192 + 4096 + w*512); \
  } while(0)

  for (int half = 0; half < 2; ++half) {
    int qt = half ? 15 - pair : pair;
    int q0 = qt * 64;
    int nt = qt + 1;

    f32x4 acc[6][4];
    #pragma unroll
    for (int i = 0; i < 6; ++i)
      #pragma unroll
      for (int j = 0; j < 4; ++j) acc[i][j] = (f32x4)0.0f;
    float m_reg = -1e30f, l_reg = 0.f;

    const u16* Qs = Q + (size_t)(q0 + srow)*EMB + scol;
    bf16x8 qreg[12][2];
    KSTAGE(Qs, 0, 0);
    KSTAGE(Qs, 1, 1);
    VMCNT2; BARRIER;
    #pragma unroll
    for (int pc = 0; pc < 6; ++pc) {
      if (pc < 4) KSTAGE(Qs, pc+2, (pc+2)%3);
      const u16* qb_ = kls + (pc%3)*8192;
      #pragma unroll
      for (int kk2 = 0; kk2 < 2; ++kk2)
        #pragma unroll
        for (int kkl = 0; kkl < 2; ++kkl)
          qreg[2*pc + kk2][kkl] = *(const bf16x8*)(qb_ + kk2*4096 + (qg*16 + frow)*64
                                                   + (((kkl*4 + (l>>4)) ^ fsw) << 3));
      if (pc < 4) { VMCNT2; } else if (pc == 4) { VMCNT0; }
      LGKM0; BARRIER;
    }

    for (int tt = 0; tt < nt; ++tt) {
      int t0 = tt*64;
      const u16* Ks = Kp + (size_t)(t0 + srow)*EMB + scol;
      const u16* Vs = Vt + (size_t)srow*MROWS + t0 + scol;
      if (tt == 0) { KSTAGE(Ks, 0, 0); KSTAGE(Ks, 1, 1); }
      VMCNT2; BARRIER;

      f32x4 sacc[2]; sacc[0] = (f32x4)0.0f; sacc[1] = (f32x4)0.0f;
      #pragma unroll
      for (int c = 0; c < 6; ++c) {
        if (c < 4)       KSTAGE(Ks, c+2, (c+2)%3);
        else if (c == 4) VSTAGE(0, 0);
        else             VSTAGE(1, 1);
        const u16* kb_ = kls + (c%3)*8192;
        __builtin_amdgcn_s_setprio(1);
        #pragma unroll
        for (int kk2 = 0; kk2 < 2; ++kk2) {
          #pragma unroll
          for (int kkl = 0; kkl < 2; ++kkl) {
            int so = ((kkl*4 + (l>>4)) ^ fsw) << 3;
            bf16x8 aq = qreg[2*c + kk2][kkl];
            #pragma unroll
            for (int cc = 0; cc < 2; ++cc) {
              bf16x8 bk_ = *(const bf16x8*)(kb_ + kk2*4096 + ((cg*2 + cc)*16 + frow)*64 + so);
              sacc[cc] = __builtin_amdgcn_mfma_f32_16x16x32_bf16(aq, bk_, sacc[cc], 0, 0, 0);
            }
          }
        }
        __builtin_amdgcn_s_setprio(0);
        if (c < 5) { VMCNT2; LGKM0; BARRIER; }
      }

      #pragma unroll
      for (int cc = 0; cc < 2; ++cc)
        #pragma unroll
        for (int r = 0; r < 4; ++r)
          s_t[(qg*16 + (l>>4)*4 + r)*68 + cg*32 + cc*16 + (l&15)] = sacc[cc][r]*SCALE_S;
      LGKM0; BARRIER;
      {
        int qglob = q0 + srow;
        int cbase = t0 + sphys*8;
        float v[8]; float mx = -1e30f;
        #pragma unroll
        for (int j = 0; j < 8; ++j) {
          float s = s_t[srow*68 + sphys*8 + j];
          if (cbase + j > qglob) s = -1e30f;
          v[j] = s; mx = fmaxf(mx, s);
        }
        mx = fmaxf(mx, __shfl_xor(mx, 1));
        mx = fmaxf(mx, __shfl_xor(mx, 2));
        mx = fmaxf(mx, __shfl_xor(mx, 4));
        float mn = fmaxf(m_reg, mx);
        float esc = __expf(m_reg - mn);
        float ps = 0.f; u16 pk[8];
        #pragma unroll
        for (int j = 0; j < 8; ++j) { float p = __expf(v[j] - mn); ps += p; pk[j] = f2bf(p); }
        ps += __shfl_xor(ps, 1); ps += __shfl_xor(ps, 2); ps += __shfl_xor(ps, 4);
        l_reg = l_reg*esc + ps; m_reg = mn;
        if (sphys == 0) e_s[srow] = esc;
        uint4 pv;
        pv.x = (uint32_t)pk[0] | ((uint32_t)pk[1] << 16);
        pv.y = (uint32_t)pk[2] | ((uint32_t)pk[3] << 16);
        pv.z = (uint32_t)pk[4] | ((uint32_t)pk[5] << 16);
        pv.w = (uint32_t)pk[6] | ((uint32_t)pk[7] << 16);
        *(uint4*)(p_t + srow*64 + ((sphys ^ (srow & 7)) << 3)) = pv;
      }
      VMCNT2; LGKM0; BARRIER;
      float er[4];
      #pragma unroll
      for (int r = 0; r < 4; ++r) er[r] = e_s[qg*16 + (l>>4)*4 + r];
      #pragma unroll
      for (int i = 0; i < 6; ++i)
        #pragma unroll
        for (int j = 0; j < 4; ++j)
          #pragma unroll
          for (int r = 0; r < 4; ++r) acc[i][j][r] *= er[r];
      bf16x8 pa[2];
      #pragma unroll
      for (int kk = 0; kk < 2; ++kk)
        pa[kk] = *(const bf16x8*)(p_t + (qg*16 + frow)*64 + (((kk*4 + (l>>4)) ^ fsw) << 3));
      bool stage_next = (tt + 1 < nt);
      const u16* Ks2 = Kp + (size_t)(t0 + 64 + srow)*EMB + scol;
      #pragma unroll
      for (int c = 0; c < 6; ++c) {
        if (c < 4)            VSTAGE(c+2, (c+2)%3);
        else if (stage_next)  { if (c == 4) KSTAGE(Ks2, 0, 0); else KSTAGE(Ks2, 1, 1); }
        const u16* vb_ = vls + (c%3)*8192;
        __builtin_amdgcn_s_setprio(1);
        #pragma unroll
        for (int cf = 0; cf < 4; ++cf) {
          #pragma unroll
          for (int kk = 0; kk < 2; ++kk) {
            bf16x8 vbf = *(const bf16x8*)(vb_ + (cg*64 + cf*16 + frow)*64 + (((kk*4 + (l>>4)) ^ fsw) << 3));
            acc[c][cf] = __builtin_amdgcn_mfma_f32_16x16x32_bf16(pa[kk], vbf, acc[c][cf], 0, 0, 0);
          }
        }
        __builtin_amdgcn_s_setprio(0);
        if (c < 4)      { VMCNT2; LGKM0; BARRIER; }
        else if (c == 4){ if (stage_next) { VMCNT2; } else { VMCNT0; } LGKM0; BARRIER; }
      }
    } // tt
    if (sphys == 0) e_s[srow] = l_reg;
    LGKM0; BARRIER;
    float linv[4];
    #pragma unroll
    for (int r = 0; r < 4; ++r) linv[r] = 1.0f / e_s[qg*16 + (l>>4)*4 + r];
    #pragma unroll
    for (int i = 0; i < 6; ++i)
      #pragma unroll
      for (int j = 0; j < 4; ++j) {
        int col = i*128 + cg*64 + j*16 + (l & 15);
        #pragma unroll
        for (int r = 0; r < 4; ++r) {
          int row = q0 + qg*16 + (l>>4)*4 + r;
          H[(size_t)row*ldh + col] = f2bf(acc[i][j][r]*linv[r]);
        }
      }
    BARRIER;
  } // half
#undef KSTAGE
#undef VSTAGE
}

// ---------------- host ----------------
extern "C" void kernel_launch(void* const* d_in, const int* in_sizes, int n_in,
                              void* d_out, int out_size, void* d_ws, size_t ws_size,
                              hipStream_t stream) {
  const float* x  = (const float*)d_in[0];
  const float* Wq = (const float*)d_in[1];
  const float* bq = (const float*)d_in[2];
  const float* Wk = (const float*)d_in[3];
  const float* bk = (const float*)d_in[4];
  const float* Wv = (const float*)d_in[5];
  const float* bv = (const float*)d_in[6];
  const float* Wc = (const float*)d_in[7];
  const float* bc = (const float*)d_in[8];
  float* out = (float*)d_out;

  const size_t XB  = (size_t)MROWS*EMB*sizeof(u16);
  const size_t WHB = (size_t)EMB*EMB*sizeof(u16);
  const size_t per_g = 4*WHB + 4*XB;
  long long avail = (long long)ws_size - (long long)XB - 4096;
  int G = (int)(avail / (long long)per_g);
  if (G < 1) G = 1;
  if (G > NHEAD) G = NHEAD;

  char* ws = (char*)d_ws;
  u16* xb  = (u16*)ws;  ws += XB;
  u16* wqb = (u16*)ws;  ws += (size_t)(2*G)*WHB;
  u16* wvb = (u16*)ws;  ws += (size_t)G*WHB;
  u16* wcb = (u16*)ws;  ws += (size_t)G*WHB;
  u16* qb  = (u16*)ws;  ws += (size_t)(2*G)*XB;
  u16* vtb = (u16*)ws;  ws += (size_t)G*XB;
  u16* hbf = (u16*)ws;  ws += (size_t)G*XB;

  k_cvt<<<dim3(3072), dim3(256), 0, stream>>>(x, xb, (long)MROWS*EMB);

  for (int h0 = 0; h0 < NHEAD; h0 += G) {
    int Gi = (G < NHEAD - h0) ? G : (NHEAD - h0);
    long nw = (long)Gi*EMB*EMB;
    k_cvt3<<<dim3((unsigned)(nw/8/256), 1, 3), dim3(256), 0, stream>>>(
        Wq + (size_t)h0*EMB*EMB, Wk + (size_t)h0*EMB*EMB, Wv + (size_t)h0*EMB*EMB,
        wqb, wqb + (size_t)Gi*EMB*EMB, wvb, nw);
    k_cvtwc<<<dim3((unsigned)((768L*Gi*EMB/4)/256)), dim3(256), 0, stream>>>(Wc, wcb, Gi, h0);
    // fused Q|K projection: C[8192, 2*Gi*768] sliced into qb (q slices then k slices)
    k_gemm256<<<dim3(32, 6*Gi), dim3(512), 0, stream>>>(
        xb, EMB, wqb, EMB, EMB,
        qb, (long)MROWS*EMB, 768,
        bq + (size_t)h0*EMB, bk + (size_t)h0*EMB, Gi, 0);
    // Vt = Wv*x^T + bv: C[Gi*768, 8192], row bias
    k_gemm256<<<dim3(3*Gi, 32), dim3(512), 0, stream>>>(
        wvb, EMB, xb, EMB, EMB,
        vtb, 0L, MROWS,
        bv + (size_t)h0*EMB, (const float*)0, 9999, 1);
    // flash attention -> hbf [8192, Gi*768]
    k_attn<<<dim3(8*NBAT*Gi), dim3(512), 0, stream>>>(
        qb, qb + (size_t)Gi*MROWS*EMB, vtb, hbf, Gi*EMB);
    // out += heads_group * Wc_group^T (+bc on first group)
    k_gemm<<<dim3(64, 6, 1), dim3(256), 0, stream>>>(
        hbf, 0L, Gi*EMB, wcb, 0L, Gi*EMB, Gi*EMB,
        (u16*)0, out, 0L, EMB,
        (h0 == 0 ? bc : (const float*)0), (const float*)0, 0L, 9999,
        (h0 == 0 ? 2 : 3), 0);
  }
}